// Round 8
// baseline (382.628 us; speedup 1.0000x reference)
//
#include <hip/hip_runtime.h>

// Problem constants
#define B_ 2
#define L_ 2048
#define D_ 2048
#define NH_ 16
#define KH_ 8
#define HD_ 128

typedef __attribute__((ext_vector_type(8))) short short8;
typedef __attribute__((ext_vector_type(4))) short short4v;
typedef __attribute__((ext_vector_type(4))) float floatx4;

__device__ __forceinline__ unsigned short f2bf(float f) {
  unsigned u = __float_as_uint(f);
  unsigned r = (u + 0x7fffu + ((u >> 16) & 1u)) >> 16;
  return (unsigned short)r;
}
__device__ __forceinline__ float bf2f(unsigned short h) {
  return __uint_as_float(((unsigned)h) << 16);
}
__device__ __forceinline__ void gl_lds16(const void* g, void* l) {
  __builtin_amdgcn_global_load_lds(
      (const __attribute__((address_space(1))) unsigned int*)g,
      (__attribute__((address_space(3))) unsigned int*)l, 16, 0, 0);
}

// ------- fused prep1: cvt x (fp32->bf16) + transpose+convert all weights -------
// id < 8192: cvt tile of x. else: weight transpose tile (task decoded).
__global__ __launch_bounds__(256) void prep1(const float* __restrict__ x,
                                             const float* __restrict__ wq,
                                             const float* __restrict__ wk,
                                             const float* __restrict__ wv,
                                             const float* __restrict__ wo,
                                             unsigned short* __restrict__ xb,
                                             unsigned short* __restrict__ wqkv_t,
                                             unsigned short* __restrict__ wo_t) {
  int id = blockIdx.x;
  int t = threadIdx.x;
  if (id < 8192) {
    long i = ((long)id * 256 + t) * 4;
    float4 v = *(const float4*)(x + i);
    ushort4 o;
    o.x = f2bf(v.x); o.y = f2bf(v.y); o.z = f2bf(v.z); o.w = f2bf(v.w);
    *(ushort4*)(xb + i) = o;
    return;
  }
  id -= 8192;
  __shared__ float tile[32][33];
  const float* in;
  unsigned short* out;
  int C, sh;
  if (id < 4096) {
    in = wq; out = wqkv_t; C = 2048; sh = 6;
  } else if (id < 6144) {
    in = wk; out = wqkv_t + 2048L * 2048; C = 1024; sh = 5; id -= 4096;
  } else if (id < 8192) {
    in = wv; out = wqkv_t + 3072L * 2048; C = 1024; sh = 5; id -= 6144;
  } else {
    in = wo; out = wo_t; C = 2048; sh = 6; id -= 8192;
  }
  int c0 = (id & ((1 << sh) - 1)) * 32, r0 = (id >> sh) * 32;
  int tx = t & 31, ty = t >> 5;  // (32, 8)
#pragma unroll
  for (int i = 0; i < 4; i++)
    tile[ty + i * 8][tx] = in[(long)(r0 + ty + i * 8) * C + c0 + tx];
  __syncthreads();
#pragma unroll
  for (int i = 0; i < 4; i++) {
    int oc = ty + i * 8;
    out[(long)(c0 + oc) * 2048 + r0 + tx] = f2bf(tile[tx][oc]);
  }
}

// ------- fused prep2: rmsrope (q,k) + transpose_v -------
// id < 24576: rmsrope (one wave per (row, head)). else: v-transpose tile.
__global__ __launch_bounds__(256) void prep2(const unsigned short* __restrict__ qkv,
                                             const int* __restrict__ pos,
                                             const float* __restrict__ qw,
                                             const float* __restrict__ kw,
                                             unsigned short* __restrict__ qo,
                                             unsigned short* __restrict__ ko,
                                             unsigned short* __restrict__ vT) {
  int id = blockIdx.x;
  int t = threadIdx.x;
  if (id < 24576) {
    const int lane = t & 63, w = t >> 6;
    const int gid = id * 4 + w;  // 0 .. 4096*24-1
    const int row = gid / 24;
    const int hd = gid - row * 24;  // 0..15 q, 16..23 k
    const int b = row >> 11, l = row & 2047;
    const unsigned short* src = qkv + (long)row * 4096 + hd * 128;
    float x0 = bf2f(src[lane]);
    float x1 = bf2f(src[lane + 64]);
    float ss = x0 * x0 + x1 * x1;
#pragma unroll
    for (int off = 32; off; off >>= 1) ss += __shfl_xor(ss, off);
    float inv = 1.0f / sqrtf(ss * (1.0f / 128.0f) + 1e-6f);
    const float* nw = (hd < 16) ? qw : kw;
    x0 = nw[lane] * x0 * inv;
    x1 = nw[lane + 64] * x1 * inv;
    float p = (float)pos[row];
    float ang = p * exp2f((float)lane * -0.31143075889f);  // 1/1e6^(lane/64)
    float s, c;
    sincosf(ang, &s, &c);
    float o0 = x0 * c - x1 * s;
    float o1 = x1 * c + x0 * s;
    unsigned short* dst;
    if (hd < 16) {
      const float QSC = 0.08838834764831845f * 1.4426950408889634f;  // H^-0.5 * log2e
      o0 *= QSC;
      o1 *= QSC;
      dst = qo + (((long)b * NH_ + hd) * L_ + l) * HD_;
    } else {
      dst = ko + (((long)b * KH_ + (hd - 16)) * L_ + l) * HD_;
    }
    dst[lane] = f2bf(o0);
    dst[lane + 64] = f2bf(o1);
    return;
  }
  id -= 24576;
  __shared__ unsigned short tile[32][33];
  int l0 = (id & 63) * 32, h0 = ((id >> 6) & 3) * 32;
  int bk = id >> 8;  // b*8 + kh
  int b = bk >> 3, kh = bk & 7;
  int tx = t & 31, ty = t >> 5;
  const unsigned short* src = qkv + (long)b * L_ * 4096 + 3072 + kh * 128;
#pragma unroll
  for (int i = 0; i < 4; i++)
    tile[ty + i * 8][tx] = src[(long)(l0 + ty + i * 8) * 4096 + h0 + tx];
  __syncthreads();
  unsigned short* dst = vT + (long)bk * HD_ * L_;
#pragma unroll
  for (int i = 0; i < 4; i++)
    dst[(long)(h0 + ty + i * 8) * L_ + l0 + tx] = tile[tx][ty + i * 8];
}

// ---------------- 128x128-tile bf16 MFMA GEMM:  C = A(MxK) * Bt(NxK)^T ----------------
// MODE: 1 = bf16 store; 2 = fp32 unsafeAtomicAdd, split-K by blockIdx.z (2 slices)
template <int MODE>
__global__ __launch_bounds__(256, 3) void gemm128(const unsigned short* __restrict__ A,
                                                  const unsigned short* __restrict__ Bt,
                                                  void* __restrict__ C,
                                                  int M, int N, int K) {
  __shared__ unsigned short As[128 * 64];
  __shared__ unsigned short Bs[128 * 64];
  const int t = threadIdx.x;
  const int lane = t & 63, w = t >> 6;
  const int wy = w >> 1, wx = w & 1;
  const int col = lane & 15, quad = lane >> 4;
  const long m0 = (long)blockIdx.y * 128, n0 = (long)blockIdx.x * 128;
  const int kbeg = (MODE == 2) ? blockIdx.z * (K >> 1) : 0;
  const int kend = (MODE == 2) ? kbeg + (K >> 1) : K;
  floatx4 acc[4][4];
#pragma unroll
  for (int i = 0; i < 4; i++)
#pragma unroll
    for (int j = 0; j < 4; j++) acc[i][j] = (floatx4)0.0f;
  const int rs = t >> 3, bs = t & 7;  // staging row / 16B-block
  for (int kt = kbeg; kt < kend; kt += 64) {
#pragma unroll
    for (int i = 0; i < 4; i++) {
      int r = i * 32 + rs;
      gl_lds16(A + (m0 + r) * (long)K + kt + ((bs ^ (r & 7)) << 3),
               &As[(i * 32 + w * 8) * 64]);
      gl_lds16(Bt + (n0 + r) * (long)K + kt + ((bs ^ (r & 7)) << 3),
               &Bs[(i * 32 + w * 8) * 64]);
    }
    __syncthreads();
#pragma unroll
    for (int ks = 0; ks < 2; ks++) {
      short8 af[4], bf[4];
#pragma unroll
      for (int mi = 0; mi < 4; mi++) {
        int row = wy * 64 + mi * 16 + col;
        int blk = ks * 4 + quad;
        af[mi] = *(const short8*)&As[row * 64 + ((blk ^ (row & 7)) << 3)];
      }
#pragma unroll
      for (int ni = 0; ni < 4; ni++) {
        int row = wx * 64 + ni * 16 + col;
        int blk = ks * 4 + quad;
        bf[ni] = *(const short8*)&Bs[row * 64 + ((blk ^ (row & 7)) << 3)];
      }
#pragma unroll
      for (int mi = 0; mi < 4; mi++)
#pragma unroll
        for (int ni = 0; ni < 4; ni++)
          acc[mi][ni] = __builtin_amdgcn_mfma_f32_16x16x32_bf16(af[mi], bf[ni],
                                                                acc[mi][ni], 0, 0, 0);
    }
    __syncthreads();
  }
#pragma unroll
  for (int mi = 0; mi < 4; mi++)
#pragma unroll
    for (int r = 0; r < 4; r++) {
      long row = m0 + wy * 64 + mi * 16 + quad * 4 + r;
#pragma unroll
      for (int ni = 0; ni < 4; ni++) {
        long cg = n0 + wx * 64 + ni * 16 + col;
        float val = acc[mi][ni][r];
        if (MODE == 1)
          ((unsigned short*)C)[row * N + cg] = f2bf(val);
        else
          unsafeAtomicAdd(&((float*)C)[row * N + cg], val);
      }
    }
}

// ------- flash attention: S^T = K Q^T + vectorized P round-trip + x32 PV -------
// S^T C-layout: each lane holds 4 CONSECUTIVE s values (s = sf*16+quad*4+r) for one
// l = w*32+mi*16+col -> P writes to [l][s] LDS are one ds_write_b64 per (mi,sf):
// 8 b64 writes/wave-step (R3 needed 32 scalar b16). PV reads P as x32 A-frags
// (4 ds_read_b128) and V as x32 B-frags (16 b128, conflict-free) -> PV at full
// mfma_16x16x32 rate (R7's 16x16x16 path was 2x the MFMA cycles).
// Fixed-max softmax: ||q||=||k||=sqrt(H) after rms-norm (RoPE is a rotation) ->
// |q.k|*H^-0.5*log2e <= 16.33 < 17 -> p = exp2(s-17), no running max / rescale.
// launch_bounds(256,2): flash needs ~170 unified regs; tighter caps spill (R4/R5).
// KV walk contiguous from s=0 keeps K/V L2-resident (R4 lesson).
__global__ __launch_bounds__(256, 2) void flash(const unsigned short* __restrict__ Q,
                                                const unsigned short* __restrict__ Kg,
                                                const unsigned short* __restrict__ VT,
                                                unsigned short* __restrict__ Og) {
  __shared__ unsigned short Ks[64 * 128];  // K tile, xor-swizzled 16B blocks
  __shared__ unsigned short Vs[128 * 64];  // V^T tile (h-major), xor-swizzled
  __shared__ unsigned short Ps[128 * 72];  // P, row l, stride 72
  const int n = blockIdx.y, b = blockIdx.z;
  const int qt = b ? (15 - blockIdx.x) : blockIdx.x;
  const int t = threadIdx.x, lane = t & 63, w = t >> 6;
  const int col = lane & 15, quad = lane >> 4;
  const int kvh = n >> 1;
  const unsigned short* kb = Kg + ((long)b * KH_ + kvh) * L_ * HD_;
  const unsigned short* vtb = VT + ((long)b * KH_ + kvh) * HD_ * L_;  // [h][l]
  const int l0 = qt * 128;
  const int steps = 2 * qt + 2;
  const unsigned short* qb = Q + (((long)b * NH_ + n) * L_ + l0) * HD_;

  // wave w owns Q rows [32w, 32w+32)
  short8 qf[2][4];
#pragma unroll
  for (int mi = 0; mi < 2; mi++)
#pragma unroll
    for (int ks = 0; ks < 4; ks++)
      qf[mi][ks] = *(const short8*)(qb + (w * 32 + mi * 16 + col) * 128 + ks * 32 + quad * 8);

  floatx4 o[2][8];  // O C-layout: rows l (quad*4+r), cols h (nf*16+col)
#pragma unroll
  for (int mi = 0; mi < 2; mi++)
#pragma unroll
    for (int nf = 0; nf < 8; nf++) o[mi][nf] = (floatx4)0.0f;
  float lrow[2] = {0.0f, 0.0f};  // partial row-sum for l = l0+w*32+mi*16+col

  for (int st = 0; st < steps; st++) {
    const int s0 = st * 64;
    // stage K tile (64 x 128): 4 x gl_lds16 per thread
    {
      const int rK = t >> 4, blkK = t & 15;
#pragma unroll
      for (int i = 0; i < 4; i++) {
        int r = i * 16 + rK;
        int gblk = (blkK & 8) | ((blkK ^ r) & 7);
        gl_lds16(kb + (long)(s0 + r) * 128 + gblk * 8, &Ks[(i * 16 + w * 4) * 128]);
      }
    }
    // stage V^T tile (128 x 64): 4 x gl_lds16 per thread
    {
      const int rV = t >> 3, blkV = t & 7;
#pragma unroll
      for (int j = 0; j < 4; j++) {
        int r = j * 32 + rV;
        int gblk = (blkV ^ r) & 7;
        gl_lds16(vtb + (long)r * L_ + s0 + gblk * 8, &Vs[(j * 32 + w * 8) * 64]);
      }
    }
    __syncthreads();

    // S^T = K Q^T: A = K-frag (LDS), B = Q-frag (regs). Rows = s, cols = l.
    floatx4 sa[2][4];
#pragma unroll
    for (int mi = 0; mi < 2; mi++)
#pragma unroll
      for (int sf = 0; sf < 4; sf++) sa[mi][sf] = (floatx4)0.0f;
#pragma unroll
    for (int ks = 0; ks < 4; ks++) {
      short8 bf[4];
#pragma unroll
      for (int sf = 0; sf < 4; sf++) {
        int srow = sf * 16 + col;
        int blk = ks * 4 + quad;
        bf[sf] = *(const short8*)&Ks[srow * 128 + (((blk & 8) | ((blk ^ srow) & 7)) << 3)];
      }
#pragma unroll
      for (int mi = 0; mi < 2; mi++)
#pragma unroll
        for (int sf = 0; sf < 4; sf++)
          sa[mi][sf] = __builtin_amdgcn_mfma_f32_16x16x32_bf16(bf[sf], qf[mi][ks],
                                                               sa[mi][sf], 0, 0, 0);
    }

    // causal mask (S^T indices: s = s0+sf*16+quad*4+r, l = l0+w*32+mi*16+col)
    if (st >= steps - 2) {
#pragma unroll
      for (int mi = 0; mi < 2; mi++) {
        int lg = l0 + w * 32 + mi * 16 + col;
#pragma unroll
        for (int sf = 0; sf < 4; sf++)
#pragma unroll
          for (int r = 0; r < 4; r++) {
            int sg = s0 + sf * 16 + quad * 4 + r;
            if (sg > lg) sa[mi][sf][r] = -3.0e38f;
          }
      }
    }

    // fixed-max softmax + vectorized P write: one ds_write_b64 per (mi,sf)
#pragma unroll
    for (int mi = 0; mi < 2; mi++)
#pragma unroll
      for (int sf = 0; sf < 4; sf++) {
        short4v pk;
#pragma unroll
        for (int r = 0; r < 4; r++) {
          float pv = exp2f(sa[mi][sf][r] - 17.0f);
          lrow[mi] += pv;
          pk[r] = (short)f2bf(pv);
        }
        *(short4v*)&Ps[(w * 32 + mi * 16 + col) * 72 + sf * 16 + quad * 4] = pk;
      }

    // O += P V at x32 rate (own P rows only -> same-wave LDS ordering, no barrier)
#pragma unroll
    for (int ks = 0; ks < 2; ks++) {
      short8 pf[2];
#pragma unroll
      for (int mi = 0; mi < 2; mi++)
        pf[mi] = *(const short8*)&Ps[(w * 32 + mi * 16 + col) * 72 + ks * 32 + quad * 8];
      short8 vf[8];
#pragma unroll
      for (int nf = 0; nf < 8; nf++) {
        int h = nf * 16 + col;
        int blk = ks * 4 + quad;
        vf[nf] = *(const short8*)&Vs[h * 64 + ((blk ^ (h & 7)) << 3)];
      }
#pragma unroll
      for (int mi = 0; mi < 2; mi++)
#pragma unroll
        for (int nf = 0; nf < 8; nf++)
          o[mi][nf] = __builtin_amdgcn_mfma_f32_16x16x32_bf16(pf[mi], vf[nf],
                                                              o[mi][nf], 0, 0, 0);
    }
    __syncthreads();
  }

  // epilogue: lrow lives transposed (per col); reduce across quads, then
  // redistribute to C-layout rows (quad*4+r) via one shuffle each.
#pragma unroll
  for (int mi = 0; mi < 2; mi++) {
    float s = lrow[mi];
    s += __shfl_xor(s, 16);
    s += __shfl_xor(s, 32);  // lanes with col=c now hold full sum for l=..+c
#pragma unroll
    for (int r = 0; r < 4; r++) {
      float inv = 1.0f / __shfl(s, quad * 4 + r);  // from lane (col=quad*4+r, quad=0)
      int lg = l0 + w * 32 + mi * 16 + quad * 4 + r;
      unsigned short* dst = Og + (((long)b * L_ + lg) * NH_ + n) * HD_;
#pragma unroll
      for (int nf = 0; nf < 8; nf++)
        dst[nf * 16 + col] = f2bf(o[mi][nf][r] * inv);
    }
  }
}

// ---------------- launcher ----------------
extern "C" void kernel_launch(void* const* d_in, const int* in_sizes, int n_in,
                              void* d_out, int out_size, void* d_ws, size_t ws_size,
                              hipStream_t stream) {
  const float* x = (const float*)d_in[0];
  const int* pos = (const int*)d_in[1];
  // d_in[2] = attn_mask (causal tril) -- implicit in the flash kernel
  const float* wq = (const float*)d_in[3];
  const float* wk = (const float*)d_in[4];
  const float* wv = (const float*)d_in[5];
  const float* wo = (const float*)d_in[6];
  const float* qnw = (const float*)d_in[7];
  const float* knw = (const float*)d_in[8];
  float* out = (float*)d_out;

  // workspace layout (bytes)
  char* ws = (char*)d_ws;
  unsigned short* xb     = (unsigned short*)(ws + 0);          // 16 MiB  (4096 x 2048 bf16)
  unsigned short* wqkv_t = (unsigned short*)(ws + 16777216);   // 16 MiB  (4096 x 2048 bf16)
  unsigned short* wo_t   = (unsigned short*)(ws + 33554432);   //  8 MiB  (2048 x 2048 bf16)
  unsigned short* qkv    = (unsigned short*)(ws + 41943040);   // 32 MiB  (4096 x 4096 bf16)
  unsigned short* q      = (unsigned short*)(ws + 75497472);   // 16 MiB  (B,N,L,H)
  unsigned short* k      = (unsigned short*)(ws + 92274688);   //  8 MiB  (B,K,L,H)
  unsigned short* vT     = (unsigned short*)(ws + 100663296);  //  8 MiB  (B,K,H,L)
  unsigned short* ao     = (unsigned short*)(ws + 109051904);  // 16 MiB  (B,L,N,H)
  if (ws_size < 125829120) return;  // insufficient workspace -> fail loudly

  hipMemsetAsync(d_out, 0, (size_t)out_size * 4, stream);
  prep1<<<20480, 256, 0, stream>>>(x, wq, wk, wv, wo, xb, wqkv_t, wo_t);
  gemm128<1><<<dim3(32, 32), 256, 0, stream>>>(xb, wqkv_t, qkv, 4096, 4096, 2048);
  prep2<<<28672, 256, 0, stream>>>(qkv, pos, qnw, knw, q, k, vT);
  flash<<<dim3(16, NH_, B_), 256, 0, stream>>>(q, k, vT, ao);
  gemm128<2><<<dim3(16, 32, 2), 256, 0, stream>>>(ao, wo_t, out, 4096, 2048, 2048);
}

// Round 9
// 361.762 us; speedup vs baseline: 1.0577x; 1.0577x over previous
//
#include <hip/hip_runtime.h>

// Problem constants
#define B_ 2
#define L_ 2048
#define D_ 2048
#define NH_ 16
#define KH_ 8
#define HD_ 128

typedef __attribute__((ext_vector_type(8))) short short8;
typedef __attribute__((ext_vector_type(4))) short short4v;
typedef __attribute__((ext_vector_type(4))) float floatx4;

__device__ __forceinline__ unsigned short f2bf(float f) {
  unsigned u = __float_as_uint(f);
  unsigned r = (u + 0x7fffu + ((u >> 16) & 1u)) >> 16;
  return (unsigned short)r;
}
__device__ __forceinline__ float bf2f(unsigned short h) {
  return __uint_as_float(((unsigned)h) << 16);
}
__device__ __forceinline__ void gl_lds16(const void* g, void* l) {
  __builtin_amdgcn_global_load_lds(
      (const __attribute__((address_space(1))) unsigned int*)g,
      (__attribute__((address_space(3))) unsigned int*)l, 16, 0, 0);
}
// Raw workgroup barrier that does NOT drain vmcnt: only our own LDS ops must be
// complete. __syncthreads() would emit s_waitcnt vmcnt(0) and kill in-flight
// register prefetch (the m97 barrier-drain stall).
__device__ __forceinline__ void barrier_lds_only() {
  asm volatile("s_waitcnt lgkmcnt(0)" ::: "memory");
  __builtin_amdgcn_s_barrier();
}

// ------- fused prep1: cvt x (fp32->bf16) + transpose+convert all weights -------
__global__ __launch_bounds__(256) void prep1(const float* __restrict__ x,
                                             const float* __restrict__ wq,
                                             const float* __restrict__ wk,
                                             const float* __restrict__ wv,
                                             const float* __restrict__ wo,
                                             unsigned short* __restrict__ xb,
                                             unsigned short* __restrict__ wqkv_t,
                                             unsigned short* __restrict__ wo_t) {
  int id = blockIdx.x;
  int t = threadIdx.x;
  if (id < 8192) {
    long i = ((long)id * 256 + t) * 4;
    float4 v = *(const float4*)(x + i);
    ushort4 o;
    o.x = f2bf(v.x); o.y = f2bf(v.y); o.z = f2bf(v.z); o.w = f2bf(v.w);
    *(ushort4*)(xb + i) = o;
    return;
  }
  id -= 8192;
  __shared__ float tile[32][33];
  const float* in;
  unsigned short* out;
  int C, sh;
  if (id < 4096) {
    in = wq; out = wqkv_t; C = 2048; sh = 6;
  } else if (id < 6144) {
    in = wk; out = wqkv_t + 2048L * 2048; C = 1024; sh = 5; id -= 4096;
  } else if (id < 8192) {
    in = wv; out = wqkv_t + 3072L * 2048; C = 1024; sh = 5; id -= 6144;
  } else {
    in = wo; out = wo_t; C = 2048; sh = 6; id -= 8192;
  }
  int c0 = (id & ((1 << sh) - 1)) * 32, r0 = (id >> sh) * 32;
  int tx = t & 31, ty = t >> 5;  // (32, 8)
#pragma unroll
  for (int i = 0; i < 4; i++)
    tile[ty + i * 8][tx] = in[(long)(r0 + ty + i * 8) * C + c0 + tx];
  __syncthreads();
#pragma unroll
  for (int i = 0; i < 4; i++) {
    int oc = ty + i * 8;
    out[(long)(c0 + oc) * 2048 + r0 + tx] = f2bf(tile[tx][oc]);
  }
}

// ------- fused prep2: rmsrope (q,k) + transpose_v -------
__global__ __launch_bounds__(256) void prep2(const unsigned short* __restrict__ qkv,
                                             const int* __restrict__ pos,
                                             const float* __restrict__ qw,
                                             const float* __restrict__ kw,
                                             unsigned short* __restrict__ qo,
                                             unsigned short* __restrict__ ko,
                                             unsigned short* __restrict__ vT) {
  int id = blockIdx.x;
  int t = threadIdx.x;
  if (id < 24576) {
    const int lane = t & 63, w = t >> 6;
    const int gid = id * 4 + w;  // 0 .. 4096*24-1
    const int row = gid / 24;
    const int hd = gid - row * 24;  // 0..15 q, 16..23 k
    const int b = row >> 11, l = row & 2047;
    const unsigned short* src = qkv + (long)row * 4096 + hd * 128;
    float x0 = bf2f(src[lane]);
    float x1 = bf2f(src[lane + 64]);
    float ss = x0 * x0 + x1 * x1;
#pragma unroll
    for (int off = 32; off; off >>= 1) ss += __shfl_xor(ss, off);
    float inv = 1.0f / sqrtf(ss * (1.0f / 128.0f) + 1e-6f);
    const float* nw = (hd < 16) ? qw : kw;
    x0 = nw[lane] * x0 * inv;
    x1 = nw[lane + 64] * x1 * inv;
    float p = (float)pos[row];
    float ang = p * exp2f((float)lane * -0.31143075889f);  // 1/1e6^(lane/64)
    float s, c;
    sincosf(ang, &s, &c);
    float o0 = x0 * c - x1 * s;
    float o1 = x1 * c + x0 * s;
    unsigned short* dst;
    if (hd < 16) {
      const float QSC = 0.08838834764831845f * 1.4426950408889634f;  // H^-0.5 * log2e
      o0 *= QSC;
      o1 *= QSC;
      dst = qo + (((long)b * NH_ + hd) * L_ + l) * HD_;
    } else {
      dst = ko + (((long)b * KH_ + (hd - 16)) * L_ + l) * HD_;
    }
    dst[lane] = f2bf(o0);
    dst[lane + 64] = f2bf(o1);
    return;
  }
  id -= 24576;
  __shared__ unsigned short tile[32][33];
  int l0 = (id & 63) * 32, h0 = ((id >> 6) & 3) * 32;
  int bk = id >> 8;  // b*8 + kh
  int b = bk >> 3, kh = bk & 7;
  int tx = t & 31, ty = t >> 5;
  const unsigned short* src = qkv + (long)b * L_ * 4096 + 3072 + kh * 128;
#pragma unroll
  for (int i = 0; i < 4; i++)
    tile[ty + i * 8][tx] = src[(long)(l0 + ty + i * 8) * 4096 + h0 + tx];
  __syncthreads();
  unsigned short* dst = vT + (long)bk * HD_ * L_;
#pragma unroll
  for (int i = 0; i < 4; i++)
    dst[(long)(h0 + ty + i * 8) * L_ + l0 + tx] = tile[tx][ty + i * 8];
}

// ---------------- 128x128-tile bf16 MFMA GEMM:  C = A(MxK) * Bt(NxK)^T ----------------
// MODE: 0 = fp32 store, 1 = bf16 store. (Split-K atomics tried R8: +22 us of extra
// output traffic (memset + RMW) at K=1024 -- reverted.)
template <int MODE>
__global__ __launch_bounds__(256, 3) void gemm128(const unsigned short* __restrict__ A,
                                                  const unsigned short* __restrict__ Bt,
                                                  void* __restrict__ C,
                                                  int M, int N, int K) {
  __shared__ unsigned short As[128 * 64];
  __shared__ unsigned short Bs[128 * 64];
  const int t = threadIdx.x;
  const int lane = t & 63, w = t >> 6;
  const int wy = w >> 1, wx = w & 1;
  const int col = lane & 15, quad = lane >> 4;
  const long m0 = (long)blockIdx.y * 128, n0 = (long)blockIdx.x * 128;
  floatx4 acc[4][4];
#pragma unroll
  for (int i = 0; i < 4; i++)
#pragma unroll
    for (int j = 0; j < 4; j++) acc[i][j] = (floatx4)0.0f;
  const int rs = t >> 3, bs = t & 7;  // staging row / 16B-block
  for (int kt = 0; kt < K; kt += 64) {
#pragma unroll
    for (int i = 0; i < 4; i++) {
      int r = i * 32 + rs;
      gl_lds16(A + (m0 + r) * (long)K + kt + ((bs ^ (r & 7)) << 3),
               &As[(i * 32 + w * 8) * 64]);
      gl_lds16(Bt + (n0 + r) * (long)K + kt + ((bs ^ (r & 7)) << 3),
               &Bs[(i * 32 + w * 8) * 64]);
    }
    __syncthreads();
#pragma unroll
    for (int ks = 0; ks < 2; ks++) {
      short8 af[4], bf[4];
#pragma unroll
      for (int mi = 0; mi < 4; mi++) {
        int row = wy * 64 + mi * 16 + col;
        int blk = ks * 4 + quad;
        af[mi] = *(const short8*)&As[row * 64 + ((blk ^ (row & 7)) << 3)];
      }
#pragma unroll
      for (int ni = 0; ni < 4; ni++) {
        int row = wx * 64 + ni * 16 + col;
        int blk = ks * 4 + quad;
        bf[ni] = *(const short8*)&Bs[row * 64 + ((blk ^ (row & 7)) << 3)];
      }
#pragma unroll
      for (int mi = 0; mi < 4; mi++)
#pragma unroll
        for (int ni = 0; ni < 4; ni++)
          acc[mi][ni] = __builtin_amdgcn_mfma_f32_16x16x32_bf16(af[mi], bf[ni],
                                                                acc[mi][ni], 0, 0, 0);
    }
    __syncthreads();
  }
#pragma unroll
  for (int mi = 0; mi < 4; mi++)
#pragma unroll
    for (int r = 0; r < 4; r++) {
      long row = m0 + wy * 64 + mi * 16 + quad * 4 + r;
#pragma unroll
      for (int ni = 0; ni < 4; ni++) {
        long cg = n0 + wx * 64 + ni * 16 + col;
        float val = acc[mi][ni][r];
        if (MODE == 1)
          ((unsigned short*)C)[row * N + cg] = f2bf(val);
        else
          ((float*)C)[row * N + cg] = val;
      }
    }
}

// ------- flash attention: S^T trick + register-prefetch double buffer -------
// S^T C-layout holds 4 consecutive s per lane -> P written with ds_write_b64 (8/step),
// PV at full x32 rate (R8). NEW: K/V tile st+1 prefetched into 32 VGPRs during
// consume-st, committed via ds_write_b128 after a RAW s_barrier with lgkmcnt(0) only
// -- __syncthreads' vmcnt(0) drain would serialize the prefetch (m97 stall pattern).
// Fixed-max softmax: ||q||=||k||=sqrt(H) -> p = exp2(s-17), no running max/rescale.
// launch_bounds(256,2): needs ~210 unified regs incl prefetch; tighter caps spill.
// KV walk contiguous from s=0 keeps K/V L2-resident (R4 lesson).
__global__ __launch_bounds__(256, 2) void flash(const unsigned short* __restrict__ Q,
                                                const unsigned short* __restrict__ Kg,
                                                const unsigned short* __restrict__ VT,
                                                unsigned short* __restrict__ Og) {
  __shared__ unsigned short Ks[64 * 128];  // K tile, xor-swizzled 16B blocks
  __shared__ unsigned short Vs[128 * 64];  // V^T tile (h-major), xor-swizzled
  __shared__ unsigned short Ps[128 * 72];  // P, row l, stride 72
  const int n = blockIdx.y, b = blockIdx.z;
  const int qt = b ? (15 - blockIdx.x) : blockIdx.x;
  const int t = threadIdx.x, lane = t & 63, w = t >> 6;
  const int col = lane & 15, quad = lane >> 4;
  const int kvh = n >> 1;
  const unsigned short* kb = Kg + ((long)b * KH_ + kvh) * L_ * HD_;
  const unsigned short* vtb = VT + ((long)b * KH_ + kvh) * HD_ * L_;  // [h][l]
  const int l0 = qt * 128;
  const int steps = 2 * qt + 2;
  const unsigned short* qb = Q + (((long)b * NH_ + n) * L_ + l0) * HD_;

  // staging geometry (same lane->address map as the gl_lds path)
  const int rK = t >> 4, blkK = t & 15;  // K: row = i*16+rK, LDS 16B-block = blkK
  const int rV = t >> 3, blkV = t & 7;   // V: row = j*32+rV, LDS 16B-block = blkV

  // wave w owns Q rows [32w, 32w+32)
  short8 qf[2][4];
#pragma unroll
  for (int mi = 0; mi < 2; mi++)
#pragma unroll
    for (int ks = 0; ks < 4; ks++)
      qf[mi][ks] = *(const short8*)(qb + (w * 32 + mi * 16 + col) * 128 + ks * 32 + quad * 8);

  floatx4 o[2][8];
#pragma unroll
  for (int mi = 0; mi < 2; mi++)
#pragma unroll
    for (int nf = 0; nf < 8; nf++) o[mi][nf] = (floatx4)0.0f;
  float lrow[2] = {0.0f, 0.0f};

  // prologue: stage tile 0 via gl_lds, full-drain barrier once
  {
#pragma unroll
    for (int i = 0; i < 4; i++) {
      int r = i * 16 + rK;
      int gblk = (blkK & 8) | ((blkK ^ r) & 7);
      gl_lds16(kb + (long)r * 128 + gblk * 8, &Ks[(i * 16 + w * 4) * 128]);
    }
#pragma unroll
    for (int j = 0; j < 4; j++) {
      int r = j * 32 + rV;
      int gblk = (blkV ^ r) & 7;
      gl_lds16(vtb + (long)r * L_ + gblk * 8, &Vs[(j * 32 + w * 8) * 64]);
    }
  }
  __syncthreads();

  short8 kpre[4], vpre[4];
  // prefetch tile 1
  if (steps > 1) {
    const int s0n = 64;
#pragma unroll
    for (int i = 0; i < 4; i++) {
      int r = i * 16 + rK;
      int gblk = (blkK & 8) | ((blkK ^ r) & 7);
      kpre[i] = *(const short8*)(kb + (long)(s0n + r) * 128 + gblk * 8);
    }
#pragma unroll
    for (int j = 0; j < 4; j++) {
      int r = j * 32 + rV;
      int gblk = (blkV ^ r) & 7;
      vpre[j] = *(const short8*)(vtb + (long)r * L_ + s0n + gblk * 8);
    }
  }

  for (int st = 0; st < steps; st++) {
    const int s0 = st * 64;

    // ---- consume tile st ----
    // S^T = K Q^T: A = K-frag (LDS), B = Q-frag (regs). Rows = s, cols = l.
    floatx4 sa[2][4];
#pragma unroll
    for (int mi = 0; mi < 2; mi++)
#pragma unroll
      for (int sf = 0; sf < 4; sf++) sa[mi][sf] = (floatx4)0.0f;
#pragma unroll
    for (int ks = 0; ks < 4; ks++) {
      short8 bf[4];
#pragma unroll
      for (int sf = 0; sf < 4; sf++) {
        int srow = sf * 16 + col;
        int blk = ks * 4 + quad;
        bf[sf] = *(const short8*)&Ks[srow * 128 + (((blk & 8) | ((blk ^ srow) & 7)) << 3)];
      }
#pragma unroll
      for (int mi = 0; mi < 2; mi++)
#pragma unroll
        for (int sf = 0; sf < 4; sf++)
          sa[mi][sf] = __builtin_amdgcn_mfma_f32_16x16x32_bf16(bf[sf], qf[mi][ks],
                                                               sa[mi][sf], 0, 0, 0);
    }

    // causal mask (S^T indices: s = s0+sf*16+quad*4+r, l = l0+w*32+mi*16+col)
    if (st >= steps - 2) {
#pragma unroll
      for (int mi = 0; mi < 2; mi++) {
        int lg = l0 + w * 32 + mi * 16 + col;
#pragma unroll
        for (int sf = 0; sf < 4; sf++)
#pragma unroll
          for (int r = 0; r < 4; r++) {
            int sg = s0 + sf * 16 + quad * 4 + r;
            if (sg > lg) sa[mi][sf][r] = -3.0e38f;
          }
      }
    }

    // fixed-max softmax + vectorized P write (one ds_write_b64 per (mi,sf))
#pragma unroll
    for (int mi = 0; mi < 2; mi++)
#pragma unroll
      for (int sf = 0; sf < 4; sf++) {
        short4v pk;
#pragma unroll
        for (int r = 0; r < 4; r++) {
          float pv = exp2f(sa[mi][sf][r] - 17.0f);
          lrow[mi] += pv;
          pk[r] = (short)f2bf(pv);
        }
        *(short4v*)&Ps[(w * 32 + mi * 16 + col) * 72 + sf * 16 + quad * 4] = pk;
      }

    // O += P V at x32 rate (own P rows only -> same-wave LDS ordering)
#pragma unroll
    for (int ks = 0; ks < 2; ks++) {
      short8 pf[2];
#pragma unroll
      for (int mi = 0; mi < 2; mi++)
        pf[mi] = *(const short8*)&Ps[(w * 32 + mi * 16 + col) * 72 + ks * 32 + quad * 8];
      short8 vf[8];
#pragma unroll
      for (int nf = 0; nf < 8; nf++) {
        int h = nf * 16 + col;
        int blk = ks * 4 + quad;
        vf[nf] = *(const short8*)&Vs[h * 64 + ((blk ^ (h & 7)) << 3)];
      }
#pragma unroll
      for (int mi = 0; mi < 2; mi++)
#pragma unroll
        for (int nf = 0; nf < 8; nf++)
          o[mi][nf] = __builtin_amdgcn_mfma_f32_16x16x32_bf16(pf[mi], vf[nf],
                                                              o[mi][nf], 0, 0, 0);
    }

    // ---- rotate buffers: raw barriers keep prefetch loads in flight ----
    barrier_lds_only();  // all waves done reading Ks/Vs (ds ops drained per-wave)
    if (st + 1 < steps) {
      // commit prefetched tile (compiler inserts vmcnt waits for the data deps here)
#pragma unroll
      for (int i = 0; i < 4; i++) {
        int r = i * 16 + rK;
        *(short8*)&Ks[r * 128 + blkK * 8] = kpre[i];
      }
#pragma unroll
      for (int j = 0; j < 4; j++) {
        int r = j * 32 + rV;
        *(short8*)&Vs[r * 64 + blkV * 8] = vpre[j];
      }
      barrier_lds_only();  // new tile visible to all waves
      if (st + 2 < steps) {
        const int s0n = (st + 2) * 64;
#pragma unroll
        for (int i = 0; i < 4; i++) {
          int r = i * 16 + rK;
          int gblk = (blkK & 8) | ((blkK ^ r) & 7);
          kpre[i] = *(const short8*)(kb + (long)(s0n + r) * 128 + gblk * 8);
        }
#pragma unroll
        for (int j = 0; j < 4; j++) {
          int r = j * 32 + rV;
          int gblk = (blkV ^ r) & 7;
          vpre[j] = *(const short8*)(vtb + (long)r * L_ + s0n + gblk * 8);
        }
      }
    }
  }

  // epilogue: lrow lives transposed (per col); reduce across quads, then
  // redistribute to C-layout rows (quad*4+r) via one shuffle each.
#pragma unroll
  for (int mi = 0; mi < 2; mi++) {
    float s = lrow[mi];
    s += __shfl_xor(s, 16);
    s += __shfl_xor(s, 32);  // lanes with col=c now hold full sum for l=..+c
#pragma unroll
    for (int r = 0; r < 4; r++) {
      float inv = 1.0f / __shfl(s, quad * 4 + r);
      int lg = l0 + w * 32 + mi * 16 + quad * 4 + r;
      unsigned short* dst = Og + (((long)b * L_ + lg) * NH_ + n) * HD_;
#pragma unroll
      for (int nf = 0; nf < 8; nf++)
        dst[nf * 16 + col] = f2bf(o[mi][nf][r] * inv);
    }
  }
}

// ---------------- launcher ----------------
extern "C" void kernel_launch(void* const* d_in, const int* in_sizes, int n_in,
                              void* d_out, int out_size, void* d_ws, size_t ws_size,
                              hipStream_t stream) {
  const float* x = (const float*)d_in[0];
  const int* pos = (const int*)d_in[1];
  // d_in[2] = attn_mask (causal tril) -- implicit in the flash kernel
  const float* wq = (const float*)d_in[3];
  const float* wk = (const float*)d_in[4];
  const float* wv = (const float*)d_in[5];
  const float* wo = (const float*)d_in[6];
  const float* qnw = (const float*)d_in[7];
  const float* knw = (const float*)d_in[8];
  float* out = (float*)d_out;

  // workspace layout (bytes)
  char* ws = (char*)d_ws;
  unsigned short* xb     = (unsigned short*)(ws + 0);          // 16 MiB  (4096 x 2048 bf16)
  unsigned short* wqkv_t = (unsigned short*)(ws + 16777216);   // 16 MiB  (4096 x 2048 bf16)
  unsigned short* wo_t   = (unsigned short*)(ws + 33554432);   //  8 MiB  (2048 x 2048 bf16)
  unsigned short* qkv    = (unsigned short*)(ws + 41943040);   // 32 MiB  (4096 x 4096 bf16)
  unsigned short* q      = (unsigned short*)(ws + 75497472);   // 16 MiB  (B,N,L,H)
  unsigned short* k      = (unsigned short*)(ws + 92274688);   //  8 MiB  (B,K,L,H)
  unsigned short* vT     = (unsigned short*)(ws + 100663296);  //  8 MiB  (B,K,H,L)
  unsigned short* ao     = (unsigned short*)(ws + 109051904);  // 16 MiB  (B,L,N,H)
  if (ws_size < 125829120) return;  // insufficient workspace -> fail loudly

  prep1<<<20480, 256, 0, stream>>>(x, wq, wk, wv, wo, xb, wqkv_t, wo_t);
  gemm128<1><<<dim3(32, 32), 256, 0, stream>>>(xb, wqkv_t, qkv, 4096, 4096, 2048);
  prep2<<<28672, 256, 0, stream>>>(qkv, pos, qnw, knw, q, k, vT);
  flash<<<dim3(16, NH_, B_), 256, 0, stream>>>(q, k, vT, ao);
  gemm128<0><<<dim3(16, 32), 256, 0, stream>>>(ao, wo_t, out, 4096, 2048, 2048);
}